// Round 8
// baseline (20.716 us; speedup 1.0000x reference)
//
#include <hip/hip_runtime.h>
#include <hip/hip_bf16.h>

#define IPS 704          // INPUTS_PER_SQUARE
#define OPS 16           // OUTPUTS_PER_SQUARE
#define NSQ 64           // NUM_SQUARES
#define MAXA 32          // MAX_ACTIVE
#define ROW_OUT 1024     // NSQ * OPS
#define SPB 4            // samples per block -> 4096 blocks = 2 generations/CU
#define NPAIR (SPB * MAXA)   // 128 (sample,feature) pairs per block

typedef float f32x4 __attribute__((ext_vector_type(4)));

__global__ __launch_bounds__(256) void ft_slice_kernel(
    const int* __restrict__ fidx,
    const float* __restrict__ fval,
    const float* __restrict__ weight,
    float* __restrict__ out)
{
    const int b0 = blockIdx.x * SPB;      // first sample of this block
    const int t  = threadIdx.x;

    __shared__ int      s_idx[NPAIR];          // 0.5 KB
    __shared__ float    s_val[NPAIR];          // 0.5 KB
    __shared__ unsigned s_mask[SPB * NSQ];     // 1 KB  per-(sample,square) bitmask
    __shared__ float    s_w[NPAIR * OPS];      // 8 KB weight rows, chunk-XOR-swizzled

    // Phase 0: stream (idx,val) with NT loads (read-once); zero masks; stage.
    int   idx = 0;
    float v   = 0.0f;
    int   sq  = 0;
    if (t < NPAIR) {
        idx = __builtin_nontemporal_load(fidx + (size_t)b0 * MAXA + t);
        v   = __builtin_nontemporal_load(fval + (size_t)b0 * MAXA + t);
        if (idx < 0) { idx = 0; v = 0.0f; }   // empty slot -> zero contribution
        sq = idx / IPS;                        // magic-mul div by const
    }
    s_mask[t] = 0u;                            // SPB*NSQ == 256 == blockDim
    if (t < NPAIR) {
        s_idx[t] = idx;
        s_val[t] = v;
    }
    __syncthreads();

    // Phase 1a: build per-(sample,square) feature bitmasks.
    if (t < NPAIR)
        atomicOr(&s_mask[(t >> 5) * NSQ + sq], 1u << (t & 31));

    // Phase 1b: prefetch ALL 128 weight rows into LDS with max MLP.
    // 4 lanes per row, each loads one float4 chunk; 2 rows per thread.
    const int my_ch = t & 3;
    #pragma unroll
    for (int c = 0; c < 2; ++c) {
        const int pair = (t >> 2) + 64 * c;
        const int ridx = s_idx[pair];                 // broadcast within lane-quad
        const f32x4 w = *reinterpret_cast<const f32x4*>(
            weight + (size_t)ridx * OPS + my_ch * 4);
        // XOR-swizzle chunk position to spread phase-2 banks
        *reinterpret_cast<f32x4*>(
            &s_w[pair * OPS + ((my_ch ^ (pair & 3)) << 2)]) = w;
    }
    __syncthreads();

    // Phase 2: thread t owns square t>>2, float4 chunk t&3, for all SPB
    // samples. LDS-only divergent loop (avg popcount 0.5/square).
    const int my_sq = t >> 2;

    unsigned masks[SPB];
    #pragma unroll
    for (int s = 0; s < SPB; ++s)
        masks[s] = s_mask[s * NSQ + my_sq];

    #pragma unroll
    for (int s = 0; s < SPB; ++s) {
        f32x4 acc = (f32x4)(0.0f);
        unsigned m = masks[s];
        while (m) {
            const int f = __builtin_ctz(m);
            m &= m - 1;
            const int pair = s * MAXA + f;
            const float vv = s_val[pair];
            const f32x4 w = *reinterpret_cast<const f32x4*>(
                &s_w[pair * OPS + ((my_ch ^ (pair & 3)) << 2)]);
            acc += vv * w;
        }
        __builtin_nontemporal_store(
            acc, reinterpret_cast<f32x4*>(out + (size_t)(b0 + s) * ROW_OUT + t * 4));
    }
}

extern "C" void kernel_launch(void* const* d_in, const int* in_sizes, int n_in,
                              void* d_out, int out_size, void* d_ws, size_t ws_size,
                              hipStream_t stream)
{
    const int*   fidx   = (const int*)d_in[0];    // (16384, 32) int32
    const float* fval   = (const float*)d_in[1];  // (16384, 32) f32
    const float* weight = (const float*)d_in[2];  // (45056, 16) f32
    float*       out    = (float*)d_out;          // (16384, 1024) f32

    const int batch = in_sizes[0] / MAXA;         // 16384
    ft_slice_kernel<<<batch / SPB, 256, 0, stream>>>(fidx, fval, weight, out);
}